// Round 4
// baseline (671.311 us; speedup 1.0000x reference)
//
#include <hip/hip_runtime.h>
#include <hip/hip_bf16.h>
#include <math.h>

#define EPSF 1e-6f
#define NLBL 159
#define NLP  160
#define HID  1024
#define BATCH 8192
#define MROWS 16
#define PS   164   // f32 row stride p0s/p1s
#define PBS  168   // ushort row stride p1b
#define SBS  1032  // ushort row stride s_b
#define K1   1836
#define K1P  1856
#define NF   150
#define NFP  160

typedef __attribute__((ext_vector_type(8))) short short8v;
typedef __attribute__((ext_vector_type(4))) float f32x4;

__device__ inline ushort f2bf(float f) {
  __hip_bfloat16 h = __float2bfloat16(f);
  return *reinterpret_cast<ushort*>(&h);
}
__device__ inline float bf2f(ushort u) {
  unsigned v = ((unsigned)u) << 16;
  return __uint_as_float(v);
}

// ---------------- threefry2x32 (exact jax semantics, 20 rounds) ----------------
__device__ inline unsigned rotl32(unsigned x, int d){ return (x<<d)|(x>>(32-d)); }

__device__ inline void threefry2x32(unsigned k0, unsigned k1,
                                    unsigned x0, unsigned x1,
                                    unsigned* o0, unsigned* o1) {
  unsigned ks0=k0, ks1=k1, ks2=k0^k1^0x1BD11BDAu;
  x0 += ks0; x1 += ks1;
#define TF_R(r) { x0 += x1; x1 = rotl32(x1,(r)); x1 ^= x0; }
  TF_R(13) TF_R(15) TF_R(26) TF_R(6)  x0 += ks1; x1 += ks2 + 1u;
  TF_R(17) TF_R(29) TF_R(16) TF_R(24) x0 += ks2; x1 += ks0 + 2u;
  TF_R(13) TF_R(15) TF_R(26) TF_R(6)  x0 += ks0; x1 += ks1 + 3u;
  TF_R(17) TF_R(29) TF_R(16) TF_R(24) x0 += ks1; x1 += ks2 + 4u;
  TF_R(13) TF_R(15) TF_R(26) TF_R(6)  x0 += ks2; x1 += ks0 + 5u;
#undef TF_R
  *o0 = x0; *o1 = x1;
}

// ---------------- generic f32 GEMM: C = act(A(MxK) @ W(NxK)^T + bias) ----------------
template<int RELU>
__global__ __launch_bounds__(256) void gemm_xwt(const float* __restrict__ A,
                                                const float* __restrict__ W,
                                                const float* __restrict__ bias,
                                                float* __restrict__ C,
                                                int M, int N, int K) {
  __shared__ float As[32][68];
  __shared__ float Ws[32][68];
  const int tid = threadIdx.x;
  const int m0 = blockIdx.x * 64;
  const int n0 = blockIdx.y * 64;
  const int tn = tid & 15;
  const int tm = tid >> 4;
  float acc[4][4];
#pragma unroll
  for (int i=0;i<4;++i)
#pragma unroll
    for (int j=0;j<4;++j) acc[i][j]=0.f;

  for (int k0 = 0; k0 < K; k0 += 32) {
    __syncthreads();
#pragma unroll
    for (int s2 = 0; s2 < 8; ++s2) {
      int f = tid + s2*256;
      int kk = f & 31, mm = f >> 5;
      int k = k0 + kk;
      float av = 0.f, wvv = 0.f;
      if (k < K) {
        av = A[(size_t)(m0+mm)*K + k];
        int n = n0 + mm;
        if (n < N) wvv = W[(size_t)n*K + k];
      }
      As[kk][mm] = av;
      Ws[kk][mm] = wvv;
    }
    __syncthreads();
    for (int kk=0; kk<32; ++kk) {
      float4 a4 = *(const float4*)&As[kk][tm*4];
      float4 b4 = *(const float4*)&Ws[kk][tn*4];
      float ai[4] = {a4.x,a4.y,a4.z,a4.w};
      float bj[4] = {b4.x,b4.y,b4.z,b4.w};
#pragma unroll
      for (int i=0;i<4;++i)
#pragma unroll
        for (int j=0;j<4;++j) acc[i][j] = fmaf(ai[i], bj[j], acc[i][j]);
    }
  }
#pragma unroll
  for (int i=0;i<4;++i)
#pragma unroll
    for (int j=0;j<4;++j) {
      int m = m0 + tm*4 + i;
      int n = n0 + tn*4 + j;
      if (n < N) {
        float v = acc[i][j] + bias[n];
        if (RELU) v = fmaxf(v, 0.f);
        C[(size_t)m*N + n] = v;
      }
    }
}

// ---------------- prep: Wg1 (1024x159 f32) -> Wg1b[1024][160] bf16, Wg1Tb[160][1024] bf16 ----------------
__global__ void prep_weights(const float* __restrict__ Wg1,
                             ushort* __restrict__ Wg1b,
                             ushort* __restrict__ Wg1Tb) {
  int idx = blockIdx.x*256 + threadIdx.x;
  if (idx >= HID*NLP) return;
  int h = idx / NLP, l = idx % NLP;
  float v = (l < NLBL) ? Wg1[h*NLBL + l] : 0.f;
  ushort b = f2bf(v);
  Wg1b[h*NLP + l]  = b;
  Wg1Tb[l*HID + h] = b;
}

// ---------------- prep: Wf1 (150x1836 f32) -> split hi/lo bf16, padded [160][1856] ----------------
__global__ void prep_wf1(const float* __restrict__ Wf1,
                         ushort* __restrict__ Wh, ushort* __restrict__ Wl) {
  int idx = blockIdx.x*256 + threadIdx.x;
  if (idx >= NFP*K1P) return;
  int n = idx / K1P, k = idx % K1P;
  float v = (n < NF && k < K1) ? Wf1[n*K1 + k] : 0.f;
  ushort h = f2bf(v);
  Wh[idx] = h;
  Wl[idx] = f2bf(v - bf2f(h));
}

// ---------------- GEMM1: h1 = relu(xs @ Wf1^T + bf1) via split-bf16 MFMA ----------------
// 256 blocks x 256 thr (4 waves); 32 rows/block; N-tiles: w0:{0,4,8} w1:{1,5,9} w2:{2,6} w3:{3,7}
__global__ __launch_bounds__(256) void gemm1_split(
    const float* __restrict__ xs, const ushort* __restrict__ Wh,
    const ushort* __restrict__ Wl, const float* __restrict__ bias,
    float* __restrict__ h1) {
  __shared__ float Asf[32*36];
  const int tid = threadIdx.x;
  const int wv = tid >> 6, lane = tid & 63;
  const int c = lane & 15, g = lane >> 4;
  const int row0 = blockIdx.x * 32;
  const int ntc = (wv < 2) ? 3 : 2;
  const int ntv[3] = {wv, wv + 4, wv + 8};

  f32x4 acc[3][2];
#pragma unroll
  for (int t = 0; t < 3; ++t)
#pragma unroll
    for (int rt = 0; rt < 2; ++rt) acc[t][rt] = (f32x4){0.f,0.f,0.f,0.f};

  const int srow = tid >> 3;
  const int skof = (tid & 7) * 4;

  for (int ks = 0; ks < K1P/32; ++ks) {
    const int k0 = ks * 32;
    const int ksrc = k0 + skof;
    const float4 av = *(const float4*)&xs[(size_t)(row0 + srow)*K1 + ((ksrc < K1) ? ksrc : 0)];
    __syncthreads();                       // previous consumers done
    *(float4*)&Asf[srow*36 + skof] = av;
    __syncthreads();                       // Asf ready
    // build A-frags (split hi/lo in-reg)
    short8v ah[2], al[2];
#pragma unroll
    for (int rt = 0; rt < 2; ++rt) {
      const float* ap = &Asf[(rt*16 + c)*36 + g*8];
      float4 x0 = *(const float4*)ap;
      float4 x1 = *(const float4*)(ap + 4);
      float xv[8] = {x0.x,x0.y,x0.z,x0.w,x1.x,x1.y,x1.z,x1.w};
#pragma unroll
      for (int j = 0; j < 8; ++j) {
        ushort hh = f2bf(xv[j]);
        ah[rt][j] = (short)hh;
        al[rt][j] = (short)f2bf(xv[j] - bf2f(hh));
      }
    }
#pragma unroll
    for (int t = 0; t < 3; ++t) {
      if (t >= ntc) break;
      const int n = ntv[t]*16 + c;
      const size_t wo = (size_t)n*K1P + k0 + g*8;
      short8v wh = *(const short8v*)&Wh[wo];
      short8v wl = *(const short8v*)&Wl[wo];
#pragma unroll
      for (int rt = 0; rt < 2; ++rt) {
        acc[t][rt] = __builtin_amdgcn_mfma_f32_16x16x32_bf16(ah[rt], wh, acc[t][rt], 0, 0, 0);
        acc[t][rt] = __builtin_amdgcn_mfma_f32_16x16x32_bf16(ah[rt], wl, acc[t][rt], 0, 0, 0);
        acc[t][rt] = __builtin_amdgcn_mfma_f32_16x16x32_bf16(al[rt], wh, acc[t][rt], 0, 0, 0);
      }
    }
  }
#pragma unroll
  for (int t = 0; t < 3; ++t) {
    if (t >= ntc) break;
    const int n = ntv[t]*16 + c;
    if (n < NF) {
      const float bv = bias[n];
#pragma unroll
      for (int rt = 0; rt < 2; ++rt)
#pragma unroll
        for (int r = 0; r < 4; ++r) {
          int m = row0 + rt*16 + g*4 + r;
          h1[(size_t)m*NF + n] = fmaxf(acc[t][rt][r] + bv, 0.f);
        }
    }
  }
}

// ---------------- persistent MFMA iteration kernel ----------------
// 512 blocks x 512 threads (8 waves); 16 rows/block; ~59KB LDS -> 2 blocks/CU.
// Phase A: waves 0,1 own 5 h-tiles; waves 2-7 own 9 (64 total).
// Phase B: wave w owns l-tile w; waves 0,1 also own l-tiles 8,9.
__global__ __launch_bounds__(512, 4) void spen_iter_mfma(
    const float* __restrict__ logits,
    const ushort* __restrict__ Wg1b,
    const ushort* __restrict__ Wg1Tb,
    const float* __restrict__ Wg2,
    float* __restrict__ out) {
  __shared__ float  p0s[MROWS*PS];
  __shared__ float  p1s[MROWS*PS];
  __shared__ ushort p1b[MROWS*PBS];
  __shared__ ushort s_b[MROWS*SBS];
  __shared__ float  u_s[NLBL];

  const int tid  = threadIdx.x;
  const int wv   = tid >> 6;
  const int lane = tid & 63;
  const int col  = lane & 15;
  const int kg   = lane >> 4;
  const int row0 = blockIdx.x * MROWS;

  // ---- pred0 via threefry (p0 = u, p1 = 1-u), bit-exact vs jax ----
  if (tid < NLBL) {
    unsigned i = 3u*(unsigned)tid + 1u;
    unsigned x0, x1; bool use1;
    if (i < 239u) { x0 = i; x1 = (i == 238u) ? 0u : (239u + i); use1 = false; }
    else          { x0 = i - 239u; x1 = i; use1 = true; }
    unsigned o0, o1;
    threefry2x32(0u, 1u, x0, x1, &o0, &o1);
    unsigned bits = use1 ? o1 : o0;
    u_s[tid] = __uint_as_float((bits >> 9) | 0x3f800000u) - 1.0f;
  }
  __syncthreads();
  for (int idx = tid; idx < MROWS*NLP; idx += 512) {
    int m = idx / NLP, l = idx % NLP;
    float u  = (l < NLBL) ? u_s[l] : 0.f;
    float p1 = (l < NLBL) ? (1.0f - u) : 0.f;
    p0s[m*PS + l]  = u;
    p1s[m*PS + l]  = p1;
    p1b[m*PBS + l] = f2bf(p1);
  }

  // ---- Phase A tile ranges ----
  const int acnt   = (wv < 2) ? 5 : 9;
  const int astart = (wv < 2) ? 5*wv : 10 + 9*(wv - 2);
  float wg2own[9];
#pragma unroll
  for (int tt = 0; tt < 9; ++tt)
    wg2own[tt] = (tt < acnt) ? Wg2[(astart + tt)*16 + col] : 0.f;

  // ---- Phase B l-columns + logits preload ----
  const bool has2 = (wv < 2);
  const int l0 = wv*16 + col;           // < 128
  const int l1 = (8 + wv)*16 + col;     // used when wv < 2
  f32x4 lg0, lg1;
#pragma unroll
  for (int r = 0; r < 4; ++r) {
    int m = row0 + kg*4 + r;
    lg0[r] = logits[(size_t)m*NLBL + l0];
    lg1[r] = (has2 && l1 < NLBL) ? logits[(size_t)m*NLBL + l1] : 0.f;
  }

  for (int it = 1; it <= 19; ++it) {
    const float lr = 1.0f / sqrtf((float)it);
    __syncthreads();            // p1b stable
    // ---------------- Phase A ----------------
    short8v afr[5];
#pragma unroll
    for (int kk = 0; kk < 5; ++kk)
      afr[kk] = *(const short8v*)&p1b[col*PBS + kk*32 + kg*8];
#pragma unroll
    for (int tt = 0; tt < 9; ++tt) {
      if (tt >= acnt) break;
      const int h = (astart + tt)*16 + col;
      f32x4 acc = (f32x4){0.f,0.f,0.f,0.f};
      const ushort* wb = &Wg1b[(size_t)h*NLP + kg*8];
#pragma unroll
      for (int kk = 0; kk < 5; ++kk)
        acc = __builtin_amdgcn_mfma_f32_16x16x32_bf16(afr[kk], *(const short8v*)(wb + kk*32), acc, 0, 0, 0);
      const float wg2v = wg2own[tt];
#pragma unroll
      for (int r = 0; r < 4; ++r) {
        float s = wg2v / (1.0f + __expf(-acc[r]));
        s_b[(kg*4 + r)*SBS + h] = f2bf(s);
      }
    }
    __syncthreads();            // s_b ready
    // ---------------- Phase B ----------------
    f32x4 b0 = (f32x4){0.f,0.f,0.f,0.f};
    f32x4 b1 = (f32x4){0.f,0.f,0.f,0.f};
    const ushort* sp  = &s_b[col*SBS + kg*8];
    const ushort* wt0 = &Wg1Tb[(size_t)l0*HID + kg*8];
    if (has2) {
      const ushort* wt1 = &Wg1Tb[(size_t)l1*HID + kg*8];
#pragma unroll 4
      for (int kk = 0; kk < 32; ++kk) {
        short8v a = *(const short8v*)(sp + kk*32);
        b0 = __builtin_amdgcn_mfma_f32_16x16x32_bf16(a, *(const short8v*)(wt0 + kk*32), b0, 0, 0, 0);
        b1 = __builtin_amdgcn_mfma_f32_16x16x32_bf16(a, *(const short8v*)(wt1 + kk*32), b1, 0, 0, 0);
      }
    } else {
#pragma unroll 4
      for (int kk = 0; kk < 32; ++kk) {
        short8v a = *(const short8v*)(sp + kk*32);
        b0 = __builtin_amdgcn_mfma_f32_16x16x32_bf16(a, *(const short8v*)(wt0 + kk*32), b0, 0, 0, 0);
      }
    }
    // ---------------- update ----------------
#define UPDATE_CELLS(LL, BACC, LGV)                                        \
    if ((LL) < NLBL) {                                                     \
      _Pragma("unroll")                                                    \
      for (int r = 0; r < 4; ++r) {                                        \
        const int m = kg*4 + r;                                            \
        float bk = (BACC)[r];                                              \
        float p1 = p1s[m*PS + (LL)];                                       \
        float p0 = p0s[m*PS + (LL)];                                       \
        float g1 = (LGV)[r] + bk - __logf(p1+EPSF) - p1/(p1+EPSF);         \
        float g0 =               - __logf(p0+EPSF) - p0/(p0+EPSF);         \
        float lg1 = lr*g1, lg0 = lr*g0;                                    \
        float mx = fmaxf(lg0, lg1);                                        \
        float e0 = p0*__expf(lg0-mx);                                      \
        float e1 = p1*__expf(lg1-mx);                                      \
        float den = e0 + e1 + EPSF;                                        \
        float n0 = e0/den, n1 = e1/den;                                    \
        p0s[m*PS + (LL)] = n0;                                             \
        p1s[m*PS + (LL)] = n1;                                             \
        p1b[m*PBS + (LL)] = f2bf(n1);                                      \
      }                                                                    \
    }
    UPDATE_CELLS(l0, b0, lg0)
    if (has2) { UPDATE_CELLS(l1, b1, lg1) }
#undef UPDATE_CELLS
  }

  __syncthreads();
  for (int idx = tid; idx < MROWS*NLBL; idx += 512) {
    int m = idx / NLBL, l = idx % NLBL;
    size_t o = ((size_t)(row0+m)*NLBL + l)*2;
    out[o]   = p0s[m*PS + l];
    out[o+1] = p1s[m*PS + l];
  }
}

extern "C" void kernel_launch(void* const* d_in, const int* in_sizes, int n_in,
                              void* d_out, int out_size, void* d_ws, size_t ws_size,
                              hipStream_t stream) {
  const float* xs  = (const float*)d_in[0];
  const float* Wf1 = (const float*)d_in[1];
  const float* bf1 = (const float*)d_in[2];
  const float* Wf2 = (const float*)d_in[3];
  const float* bf2 = (const float*)d_in[4];
  const float* Wf3 = (const float*)d_in[5];
  const float* bf3 = (const float*)d_in[6];
  const float* Wg1 = (const float*)d_in[7];
  const float* Wg2 = (const float*)d_in[8];
  float* out = (float*)d_out;

  float* h1     = (float*)d_ws;                 // 8192*150
  float* h2     = h1 + (size_t)BATCH*NF;        // 8192*150
  float* logits = h2 + (size_t)BATCH*NF;        // 8192*159
  ushort* Wg1b  = (ushort*)(logits + (size_t)BATCH*NLBL);  // 1024*160 bf16
  ushort* Wg1Tb = Wg1b + (size_t)HID*NLP;                  // 160*1024 bf16
  ushort* Wf1h  = Wg1Tb + (size_t)NLP*HID;                 // 160*1856 bf16
  ushort* Wf1l  = Wf1h + (size_t)NFP*K1P;                  // 160*1856 bf16

  prep_wf1<<<(NFP*K1P + 255)/256, 256, 0, stream>>>(Wf1, Wf1h, Wf1l);
  prep_weights<<<(HID*NLP + 255)/256, 256, 0, stream>>>(Wg1, Wg1b, Wg1Tb);

  gemm1_split<<<BATCH/32, 256, 0, stream>>>(xs, Wf1h, Wf1l, bf1, h1);
  gemm_xwt<1><<<dim3(BATCH/64, 3), 256, 0, stream>>>(h1, Wf2, bf2, h2, BATCH, NF, NF);
  gemm_xwt<0><<<dim3(BATCH/64, 3), 256, 0, stream>>>(h2, Wf3, bf3, logits, BATCH, NLBL, NF);

  spen_iter_mfma<<<BATCH/MROWS, 512, 0, stream>>>(logits, Wg1b, Wg1Tb, Wg2, out);
}

// Round 5
// 525.489 us; speedup vs baseline: 1.2775x; 1.2775x over previous
//
#include <hip/hip_runtime.h>
#include <hip/hip_bf16.h>
#include <math.h>

#define EPSF 1e-6f
#define NLBL 159
#define NLP  160
#define HID  1024
#define BATCH 8192
#define MROWS 32
#define PBS  168   // ushort row stride p1b
#define SBS  1044  // ushort row stride s_b (522 dw = 10 mod 32 -> conflict-free)
#define K1   1836
#define K1P  1856
#define NF   150
#define NFP  160

typedef __attribute__((ext_vector_type(8))) short short8v;
typedef __attribute__((ext_vector_type(4))) float f32x4;

__device__ inline ushort f2bf(float f) {
  __hip_bfloat16 h = __float2bfloat16(f);
  return *reinterpret_cast<ushort*>(&h);
}
__device__ inline float bf2f(ushort u) {
  unsigned v = ((unsigned)u) << 16;
  return __uint_as_float(v);
}
__device__ inline float rcpf(float x) { return __builtin_amdgcn_rcpf(x); }
__device__ inline float sigmoidf(float x) { return rcpf(1.0f + __expf(-x)); }

// ---------------- threefry2x32 (exact jax semantics, 20 rounds) ----------------
__device__ inline unsigned rotl32(unsigned x, int d){ return (x<<d)|(x>>(32-d)); }

__device__ inline void threefry2x32(unsigned k0, unsigned k1,
                                    unsigned x0, unsigned x1,
                                    unsigned* o0, unsigned* o1) {
  unsigned ks0=k0, ks1=k1, ks2=k0^k1^0x1BD11BDAu;
  x0 += ks0; x1 += ks1;
#define TF_R(r) { x0 += x1; x1 = rotl32(x1,(r)); x1 ^= x0; }
  TF_R(13) TF_R(15) TF_R(26) TF_R(6)  x0 += ks1; x1 += ks2 + 1u;
  TF_R(17) TF_R(29) TF_R(16) TF_R(24) x0 += ks2; x1 += ks0 + 2u;
  TF_R(13) TF_R(15) TF_R(26) TF_R(6)  x0 += ks0; x1 += ks1 + 3u;
  TF_R(17) TF_R(29) TF_R(16) TF_R(24) x0 += ks1; x1 += ks2 + 4u;
  TF_R(13) TF_R(15) TF_R(26) TF_R(6)  x0 += ks2; x1 += ks0 + 5u;
#undef TF_R
  *o0 = x0; *o1 = x1;
}

// ---------------- generic f32 GEMM: C = act(A(MxK) @ W(NxK)^T + bias) ----------------
template<int RELU>
__global__ __launch_bounds__(256) void gemm_xwt(const float* __restrict__ A,
                                                const float* __restrict__ W,
                                                const float* __restrict__ bias,
                                                float* __restrict__ C,
                                                int M, int N, int K) {
  __shared__ float As[32][68];
  __shared__ float Ws[32][68];
  const int tid = threadIdx.x;
  const int m0 = blockIdx.x * 64;
  const int n0 = blockIdx.y * 64;
  const int tn = tid & 15;
  const int tm = tid >> 4;
  float acc[4][4];
#pragma unroll
  for (int i=0;i<4;++i)
#pragma unroll
    for (int j=0;j<4;++j) acc[i][j]=0.f;

  for (int k0 = 0; k0 < K; k0 += 32) {
    __syncthreads();
#pragma unroll
    for (int s2 = 0; s2 < 8; ++s2) {
      int f = tid + s2*256;
      int kk = f & 31, mm = f >> 5;
      int k = k0 + kk;
      float av = 0.f, wvv = 0.f;
      if (k < K) {
        av = A[(size_t)(m0+mm)*K + k];
        int n = n0 + mm;
        if (n < N) wvv = W[(size_t)n*K + k];
      }
      As[kk][mm] = av;
      Ws[kk][mm] = wvv;
    }
    __syncthreads();
    for (int kk=0; kk<32; ++kk) {
      float4 a4 = *(const float4*)&As[kk][tm*4];
      float4 b4 = *(const float4*)&Ws[kk][tn*4];
      float ai[4] = {a4.x,a4.y,a4.z,a4.w};
      float bj[4] = {b4.x,b4.y,b4.z,b4.w};
#pragma unroll
      for (int i=0;i<4;++i)
#pragma unroll
        for (int j=0;j<4;++j) acc[i][j] = fmaf(ai[i], bj[j], acc[i][j]);
    }
  }
#pragma unroll
  for (int i=0;i<4;++i)
#pragma unroll
    for (int j=0;j<4;++j) {
      int m = m0 + tm*4 + i;
      int n = n0 + tn*4 + j;
      if (n < N) {
        float v = acc[i][j] + bias[n];
        if (RELU) v = fmaxf(v, 0.f);
        C[(size_t)m*N + n] = v;
      }
    }
}

// ---------------- prep: Wg1 (1024x159 f32) -> Wg1b[1024][160] bf16, Wg1Tb[160][1024] bf16 ----------------
__global__ void prep_weights(const float* __restrict__ Wg1,
                             ushort* __restrict__ Wg1b,
                             ushort* __restrict__ Wg1Tb) {
  int idx = blockIdx.x*256 + threadIdx.x;
  if (idx >= HID*NLP) return;
  int h = idx / NLP, l = idx % NLP;
  float v = (l < NLBL) ? Wg1[h*NLBL + l] : 0.f;
  ushort b = f2bf(v);
  Wg1b[h*NLP + l]  = b;
  Wg1Tb[l*HID + h] = b;
}

// ---------------- prep: Wf1 (150x1836 f32) -> split hi/lo bf16, padded [160][1856] ----------------
__global__ void prep_wf1(const float* __restrict__ Wf1,
                         ushort* __restrict__ Wh, ushort* __restrict__ Wl) {
  int idx = blockIdx.x*256 + threadIdx.x;
  if (idx >= NFP*K1P) return;
  int n = idx / K1P, k = idx % K1P;
  float v = (n < NF && k < K1) ? Wf1[n*K1 + k] : 0.f;
  ushort h = f2bf(v);
  Wh[idx] = h;
  Wl[idx] = f2bf(v - bf2f(h));
}

// ---------------- GEMM1: h1 = relu(xs @ Wf1^T + bf1) via split-bf16 MFMA ----------------
__global__ __launch_bounds__(256) void gemm1_split(
    const float* __restrict__ xs, const ushort* __restrict__ Wh,
    const ushort* __restrict__ Wl, const float* __restrict__ bias,
    float* __restrict__ h1) {
  __shared__ float Asf[32*36];
  const int tid = threadIdx.x;
  const int wv = tid >> 6, lane = tid & 63;
  const int c = lane & 15, g = lane >> 4;
  const int row0 = blockIdx.x * 32;
  const int ntc = (wv < 2) ? 3 : 2;
  const int ntv[3] = {wv, wv + 4, wv + 8};

  f32x4 acc[3][2];
#pragma unroll
  for (int t = 0; t < 3; ++t)
#pragma unroll
    for (int rt = 0; rt < 2; ++rt) acc[t][rt] = (f32x4){0.f,0.f,0.f,0.f};

  const int srow = tid >> 3;
  const int skof = (tid & 7) * 4;

  for (int ks = 0; ks < K1P/32; ++ks) {
    const int k0 = ks * 32;
    const int ksrc = k0 + skof;
    const float4 av = *(const float4*)&xs[(size_t)(row0 + srow)*K1 + ((ksrc < K1) ? ksrc : 0)];
    __syncthreads();
    *(float4*)&Asf[srow*36 + skof] = av;
    __syncthreads();
    short8v ah[2], al[2];
#pragma unroll
    for (int rt = 0; rt < 2; ++rt) {
      const float* ap = &Asf[(rt*16 + c)*36 + g*8];
      float4 x0 = *(const float4*)ap;
      float4 x1 = *(const float4*)(ap + 4);
      float xv[8] = {x0.x,x0.y,x0.z,x0.w,x1.x,x1.y,x1.z,x1.w};
#pragma unroll
      for (int j = 0; j < 8; ++j) {
        ushort hh = f2bf(xv[j]);
        ah[rt][j] = (short)hh;
        al[rt][j] = (short)f2bf(xv[j] - bf2f(hh));
      }
    }
#pragma unroll
    for (int t = 0; t < 3; ++t) {
      if (t >= ntc) break;
      const int n = ntv[t]*16 + c;
      const size_t wo = (size_t)n*K1P + k0 + g*8;
      short8v wh = *(const short8v*)&Wh[wo];
      short8v wl = *(const short8v*)&Wl[wo];
#pragma unroll
      for (int rt = 0; rt < 2; ++rt) {
        acc[t][rt] = __builtin_amdgcn_mfma_f32_16x16x32_bf16(ah[rt], wh, acc[t][rt], 0, 0, 0);
        acc[t][rt] = __builtin_amdgcn_mfma_f32_16x16x32_bf16(ah[rt], wl, acc[t][rt], 0, 0, 0);
        acc[t][rt] = __builtin_amdgcn_mfma_f32_16x16x32_bf16(al[rt], wh, acc[t][rt], 0, 0, 0);
      }
    }
  }
#pragma unroll
  for (int t = 0; t < 3; ++t) {
    if (t >= ntc) break;
    const int n = ntv[t]*16 + c;
    if (n < NF) {
      const float bv = bias[n];
#pragma unroll
      for (int rt = 0; rt < 2; ++rt)
#pragma unroll
        for (int r = 0; r < 4; ++r) {
          int m = row0 + rt*16 + g*4 + r;
          h1[(size_t)m*NF + n] = fmaxf(acc[t][rt][r] + bv, 0.f);
        }
    }
  }
}

// ---------------- persistent MFMA iteration kernel (q-space, static phases) ----------------
// 256 blocks x 512 threads (8 waves); 32 rows/block; 1 block/CU.
// Phase A: wave w owns h-tiles {8w..8w+7} (static, double-buffered weight stream).
// Phase B: wave w owns l-tile w; waves 0,1 also own l-tiles 8,9.
// State q = log(p1/p0) kept in registers of the owning thread.
__global__ __launch_bounds__(512, 2) void spen_iter_mfma(
    const float* __restrict__ logits,
    const ushort* __restrict__ Wg1b,
    const ushort* __restrict__ Wg1Tb,
    const float* __restrict__ Wg2,
    float* __restrict__ out) {
  __shared__ ushort p1b[MROWS*PBS];
  __shared__ ushort s_b[MROWS*SBS];
  __shared__ float  u_s[NLBL];

  const int tid  = threadIdx.x;
  const int wv   = tid >> 6;
  const int lane = tid & 63;
  const int col  = lane & 15;
  const int kg   = lane >> 4;
  const int row0 = blockIdx.x * MROWS;

  // ---- pred0 via threefry (p0 = u, p1 = 1-u), bit-exact vs jax ----
  if (tid < NLBL) {
    unsigned i = 3u*(unsigned)tid + 1u;
    unsigned x0, x1; bool use1;
    if (i < 239u) { x0 = i; x1 = (i == 238u) ? 0u : (239u + i); use1 = false; }
    else          { x0 = i - 239u; x1 = i; use1 = true; }
    unsigned o0, o1;
    threefry2x32(0u, 1u, x0, x1, &o0, &o1);
    unsigned bits = use1 ? o1 : o0;
    u_s[tid] = __uint_as_float((bits >> 9) | 0x3f800000u) - 1.0f;
  }
  __syncthreads();
  for (int idx = tid; idx < MROWS*NLP; idx += 512) {
    int m = idx / NLP, l = idx % NLP;
    float p1 = (l < NLBL) ? (1.0f - u_s[l]) : 0.f;
    p1b[m*PBS + l] = f2bf(p1);
  }

  // ---- ownership ----
  const bool has2 = (wv < 2);
  const int l0 = wv*16 + col;            // 0..127, always valid
  const int l1 = 128 + wv*16 + col;      // 128..159; l1==159 invalid
  const bool v1 = has2 && (l1 < NLBL);

  // ---- q-state init ----
  float q0[8], q1[8];
  {
    float u0v = u_s[l0];
    float qi0 = __logf((1.0f - u0v) * rcpf(u0v));
    float qi1 = 0.f;
    if (v1) { float u1v = u_s[l1]; qi1 = __logf((1.0f - u1v) * rcpf(u1v)); }
#pragma unroll
    for (int i = 0; i < 8; ++i) { q0[i] = qi0; q1[i] = qi1; }
  }

  // ---- constant preloads ----
  float wg2own[8];
#pragma unroll
  for (int tt = 0; tt < 8; ++tt) wg2own[tt] = Wg2[(wv*8 + tt)*16 + col];

  float lg0[8], lg1[8];
#pragma unroll
  for (int rh = 0; rh < 2; ++rh)
#pragma unroll
    for (int r = 0; r < 4; ++r) {
      int m = row0 + rh*16 + kg*4 + r;
      lg0[rh*4+r] = logits[(size_t)m*NLBL + l0];
      lg1[rh*4+r] = v1 ? logits[(size_t)m*NLBL + l1] : 0.f;
    }

  const ushort* wbase = Wg1b + ((size_t)(wv*8)*16 + col)*NLP + kg*8;

  for (int it = 1; it <= 19; ++it) {
    const float lr = rsqrtf((float)it);
    __syncthreads();            // p1b stable for all waves
    // ---------------- Phase A: z = p1 @ Wg1^T, s = Wg2*sigmoid(z) ----------------
    short8v afr0[5], afr1[5];
#pragma unroll
    for (int kk = 0; kk < 5; ++kk) {
      afr0[kk] = *(const short8v*)&p1b[col*PBS + kk*32 + kg*8];
      afr1[kk] = *(const short8v*)&p1b[(16 + col)*PBS + kk*32 + kg*8];
    }
    short8v wA[2][5];
#pragma unroll
    for (int kk = 0; kk < 5; ++kk) wA[0][kk] = *(const short8v*)(wbase + kk*32);
#pragma unroll
    for (int tt = 0; tt < 8; ++tt) {
      const int cur = tt & 1;
      if (tt < 7) {
        const ushort* wp = wbase + (size_t)((tt + 1)*16)*NLP;
#pragma unroll
        for (int kk = 0; kk < 5; ++kk) wA[cur^1][kk] = *(const short8v*)(wp + kk*32);
      }
      f32x4 a0 = (f32x4){0.f,0.f,0.f,0.f};
      f32x4 a1 = (f32x4){0.f,0.f,0.f,0.f};
#pragma unroll
      for (int kk = 0; kk < 5; ++kk) {
        a0 = __builtin_amdgcn_mfma_f32_16x16x32_bf16(afr0[kk], wA[cur][kk], a0, 0, 0, 0);
        a1 = __builtin_amdgcn_mfma_f32_16x16x32_bf16(afr1[kk], wA[cur][kk], a1, 0, 0, 0);
      }
      const int h = (wv*8 + tt)*16 + col;
      const float wg2v = wg2own[tt];
#pragma unroll
      for (int r = 0; r < 4; ++r) {
        s_b[(kg*4 + r)*SBS + h]      = f2bf(wg2v * sigmoidf(a0[r]));
        s_b[(16 + kg*4 + r)*SBS + h] = f2bf(wg2v * sigmoidf(a1[r]));
      }
    }
    __syncthreads();            // s_b complete
    // ---------------- Phase B: back = s @ Wg1 ----------------
    f32x4 bA0 = (f32x4){0.f,0.f,0.f,0.f};
    f32x4 bA1 = (f32x4){0.f,0.f,0.f,0.f};
    f32x4 bB0 = (f32x4){0.f,0.f,0.f,0.f};
    f32x4 bB1 = (f32x4){0.f,0.f,0.f,0.f};
    const ushort* sp0 = &s_b[col*SBS + kg*8];
    const ushort* sp1 = &s_b[(16 + col)*SBS + kg*8];
    const ushort* wt0 = &Wg1Tb[(size_t)l0*HID + kg*8];
    if (has2) {
      const ushort* wt1 = &Wg1Tb[(size_t)l1*HID + kg*8];
#pragma unroll
      for (int kk = 0; kk < 32; ++kk) {
        short8v w0 = *(const short8v*)(wt0 + kk*32);
        short8v w1 = *(const short8v*)(wt1 + kk*32);
        short8v a0 = *(const short8v*)(sp0 + kk*32);
        short8v a1 = *(const short8v*)(sp1 + kk*32);
        bA0 = __builtin_amdgcn_mfma_f32_16x16x32_bf16(a0, w0, bA0, 0, 0, 0);
        bA1 = __builtin_amdgcn_mfma_f32_16x16x32_bf16(a1, w0, bA1, 0, 0, 0);
        bB0 = __builtin_amdgcn_mfma_f32_16x16x32_bf16(a0, w1, bB0, 0, 0, 0);
        bB1 = __builtin_amdgcn_mfma_f32_16x16x32_bf16(a1, w1, bB1, 0, 0, 0);
      }
    } else {
#pragma unroll
      for (int kk = 0; kk < 32; ++kk) {
        short8v w0 = *(const short8v*)(wt0 + kk*32);
        short8v a0 = *(const short8v*)(sp0 + kk*32);
        short8v a1 = *(const short8v*)(sp1 + kk*32);
        bA0 = __builtin_amdgcn_mfma_f32_16x16x32_bf16(a0, w0, bA0, 0, 0, 0);
        bA1 = __builtin_amdgcn_mfma_f32_16x16x32_bf16(a1, w0, bA1, 0, 0, 0);
      }
    }
    // ---------------- update (q-space, owned cells in regs) ----------------
#define UPDATE_ONE(QARR, IDX, LGV, BK, LL, MM)                               \
    {                                                                        \
      float q = QARR[IDX];                                                   \
      float p1v = sigmoidf(q);                                               \
      float p0v = 1.0f - p1v;                                                \
      float rp1 = rcpf(p1v + EPSF);                                          \
      float rp0 = rcpf(p0v + EPSF);                                          \
      float dlt = (LGV) + (BK) - __logf((p1v + EPSF)*rp0) - p1v*rp1 + p0v*rp0;\
      q += lr*dlt;                                                           \
      QARR[IDX] = q;                                                         \
      p1b[(MM)*PBS + (LL)] = f2bf(sigmoidf(q));                              \
    }
#pragma unroll
    for (int r = 0; r < 4; ++r) {
      const int m0r = kg*4 + r;
      UPDATE_ONE(q0, r, lg0[r], bA0[r], l0, m0r)
      const int m1r = 16 + kg*4 + r;
      UPDATE_ONE(q0, 4 + r, lg0[4 + r], bA1[r], l0, m1r)
    }
    if (v1) {
#pragma unroll
      for (int r = 0; r < 4; ++r) {
        const int m0r = kg*4 + r;
        UPDATE_ONE(q1, r, lg1[r], bB0[r], l1, m0r)
        const int m1r = 16 + kg*4 + r;
        UPDATE_ONE(q1, 4 + r, lg1[4 + r], bB1[r], l1, m1r)
      }
    }
#undef UPDATE_ONE
  }

  // ---------------- final write (once) ----------------
#pragma unroll
  for (int rh = 0; rh < 2; ++rh)
#pragma unroll
    for (int r = 0; r < 4; ++r) {
      const int row = row0 + rh*16 + kg*4 + r;
      float p1v = sigmoidf(q0[rh*4 + r]);
      size_t o = ((size_t)row*NLBL + l0)*2;
      out[o]   = 1.0f - p1v;
      out[o+1] = p1v;
      if (v1) {
        float p1w = sigmoidf(q1[rh*4 + r]);
        size_t o2 = ((size_t)row*NLBL + l1)*2;
        out[o2]   = 1.0f - p1w;
        out[o2+1] = p1w;
      }
    }
}

extern "C" void kernel_launch(void* const* d_in, const int* in_sizes, int n_in,
                              void* d_out, int out_size, void* d_ws, size_t ws_size,
                              hipStream_t stream) {
  const float* xs  = (const float*)d_in[0];
  const float* Wf1 = (const float*)d_in[1];
  const float* bf1 = (const float*)d_in[2];
  const float* Wf2 = (const float*)d_in[3];
  const float* bf2 = (const float*)d_in[4];
  const float* Wf3 = (const float*)d_in[5];
  const float* bf3 = (const float*)d_in[6];
  const float* Wg1 = (const float*)d_in[7];
  const float* Wg2 = (const float*)d_in[8];
  float* out = (float*)d_out;

  float* h1     = (float*)d_ws;                 // 8192*150
  float* h2     = h1 + (size_t)BATCH*NF;        // 8192*150
  float* logits = h2 + (size_t)BATCH*NF;        // 8192*159
  ushort* Wg1b  = (ushort*)(logits + (size_t)BATCH*NLBL);  // 1024*160 bf16
  ushort* Wg1Tb = Wg1b + (size_t)HID*NLP;                  // 160*1024 bf16
  ushort* Wf1h  = Wg1Tb + (size_t)NLP*HID;                 // 160*1856 bf16
  ushort* Wf1l  = Wf1h + (size_t)NFP*K1P;                  // 160*1856 bf16

  prep_wf1<<<(NFP*K1P + 255)/256, 256, 0, stream>>>(Wf1, Wf1h, Wf1l);
  prep_weights<<<(HID*NLP + 255)/256, 256, 0, stream>>>(Wg1, Wg1b, Wg1Tb);

  gemm1_split<<<BATCH/32, 256, 0, stream>>>(xs, Wf1h, Wf1l, bf1, h1);
  gemm_xwt<1><<<dim3(BATCH/64, 3), 256, 0, stream>>>(h1, Wf2, bf2, h2, BATCH, NF, NF);
  gemm_xwt<0><<<dim3(BATCH/64, 3), 256, 0, stream>>>(h2, Wf3, bf3, logits, BATCH, NLBL, NF);

  spen_iter_mfma<<<BATCH/MROWS, 512, 0, stream>>>(logits, Wg1b, Wg1Tb, Wg2, out);
}